// Round 11
// baseline (94.577 us; speedup 1.0000x reference)
//
#include <hip/hip_runtime.h>

// WaveletFeatureExtractor: db4 wavedec (5 levels, symmetric pad) -> adaptive pool 128
// -> per-level 128x128 MLP (ReLU) -> fused 640->512 MLP (ReLU).
//
// Round 11: polyphase (even/odd deinterleaved) LDS bands replace the XOR swizzle.
// out[j] = sum_s LO[2s]E[j-3+s] + LO[2s+1]O[j-3+s]; window reads are contiguous
// b128 (conflict-free at 16B lane stride) with immediate offsets -> all SWZ
// address VALU (~20% of the stream) deleted. cA written phase-split (float2 x2);
// cD + cA5 linear (b128 write conflict-free, pool reads contiguous no-SWZ).
// Geometry constexpr via dwt_body<B> (r10). 37.9KB LDS -> 4 blocks/CU (r9).
// mlp: r8 (f16 pre-packed weights, 1024 thr, dot2).

#define BATCH   2048
#define SIGLEN  16384
#define N1      8195
#define N2      4101
#define N3      2054
#define N4      1030
#define N5      518
#define POOLP   128
#define COMB    640
#define OUTD    512
#define NTHR    512

__device__ constexpr float LO[8] = {
     0.2303778133088965f,   0.7148465705529157f,   0.6308807679298589f,
    -0.027983769416859854f, -0.18703481171909309f,  0.030841381835560764f,
     0.0328830116668852f,  -0.010597401785069032f };
__device__ constexpr float HI[8] = {
    -0.010597401785069032f, -0.0328830116668852f,   0.030841381835560764f,
     0.18703481171909309f,  -0.027983769416859854f, -0.6308807679298589f,
     0.7148465705529157f,  -0.2303778133088965f };

__device__ __forceinline__ int symfold(int idx, int n) {
    idx = (idx < 0) ? (-1 - idx) : idx;
    idx = (idx >= n) ? (2 * n - 1 - idx) : idx;
    return idx;
}

constexpr int cmin(int a, int b) { return a < b ? a : b; }
constexpr int cmax(int a, int b) { return a > b ? a : b; }

// One DWT level, polyphase source. Source band chunk [SS,SE) stored as
// srcE[m-BPS]=band[2m], srcO[m-BPS]=band[2m+1]. Outputs [S,E):
//  - ALIN=false: cA phase-split at dstAE/dstAO[(j>>1)-BPD]; cD linear at dstD[j-BD]
//  - ALIN=true : cA LINEAR at dstAE[j-BPD] (cA5 is only pooled); cD same.
template<int SS, int SE, int BPS, int NSRC, int S, int E, int BPD, int BD, bool ALIN>
__device__ __forceinline__ void dwt_lvl(const float* __restrict__ srcE,
                                        const float* __restrict__ srcO,
                                        float* __restrict__ dstAE,
                                        float* __restrict__ dstAO,
                                        float* __restrict__ dstD,
                                        int tid) {
    for (int j0 = (S & ~3) + tid * 4; j0 < E; j0 += NTHR * 4) {
        if ((2 * j0 - 8 >= SS) && (2 * j0 + 7 <= SE - 1) && (j0 + 4 <= E)) {
            const int off = j0 - 4 - BPS;           // E/O window m = j0-4 .. j0+3
            const float4 e0 = *reinterpret_cast<const float4*>(srcE + off);
            const float4 e1 = *reinterpret_cast<const float4*>(srcE + off + 4);
            const float4 o0 = *reinterpret_cast<const float4*>(srcO + off);
            const float4 o1 = *reinterpret_cast<const float4*>(srcO + off + 4);
            const float ew[8] = {e0.x, e0.y, e0.z, e0.w, e1.x, e1.y, e1.z, e1.w};
            const float ow[8] = {o0.x, o0.y, o0.z, o0.w, o1.x, o1.y, o1.z, o1.w};
            float a[4], d[4];
#pragma unroll
            for (int k = 0; k < 4; ++k) {
                float aa = 0.f, dd = 0.f;
#pragma unroll
                for (int s = 0; s < 4; ++s) {
                    const float ve = ew[k + 1 + s], vo = ow[k + 1 + s];
                    aa = fmaf(ve, LO[2 * s], aa); aa = fmaf(vo, LO[2 * s + 1], aa);
                    dd = fmaf(ve, HI[2 * s], dd); dd = fmaf(vo, HI[2 * s + 1], dd);
                }
                a[k] = aa; d[k] = dd;
            }
            if constexpr (ALIN) {
                *reinterpret_cast<float4*>(dstAE + (j0 - BPD)) = make_float4(a[0], a[1], a[2], a[3]);
            } else {
                const int m0 = (j0 >> 1) - BPD;
                *reinterpret_cast<float2*>(dstAE + m0) = make_float2(a[0], a[2]);
                *reinterpret_cast<float2*>(dstAO + m0) = make_float2(a[1], a[3]);
            }
            *reinterpret_cast<float4*>(dstD + (j0 - BD)) = make_float4(d[0], d[1], d[2], d[3]);
        } else {
            for (int k = 0; k < 4; ++k) {
                const int j = j0 + k;
                if (j < S || j >= E) continue;
                float aa = 0.f, dd = 0.f;
#pragma unroll
                for (int t = 0; t < 8; ++t) {
                    const int idx = symfold(2 * j - 6 + t, NSRC);
                    const float v = (idx & 1) ? srcO[(idx >> 1) - BPS] : srcE[(idx >> 1) - BPS];
                    aa = fmaf(v, LO[t], aa);
                    dd = fmaf(v, HI[t], dd);
                }
                if constexpr (ALIN) {
                    dstAE[j - BPD] = aa;
                } else {
                    if (j & 1) dstAO[(j >> 1) - BPD] = aa;
                    else       dstAE[(j >> 1) - BPD] = aa;
                }
                dstD[j - BD] = dd;
            }
        }
    }
}

// Level 1 from global interleaved x (low-pass only; cD1 dead). Phase-split dst.
template<int S, int E, int BPD>
__device__ __forceinline__ void dwt_l1(const float* __restrict__ xr,
                                       float* __restrict__ dstAE,
                                       float* __restrict__ dstAO,
                                       int tid) {
    for (int j0 = (S & ~3) + tid * 4; j0 < E; j0 += NTHR * 4) {
        const int rb = 2 * j0 - 8;
        if ((rb >= 0) && (2 * j0 + 7 <= SIGLEN - 1) && (j0 + 4 <= E)) {
            const float4* s4 = reinterpret_cast<const float4*>(xr + rb);
            const float4 v0 = s4[0], v1 = s4[1], v2 = s4[2], v3 = s4[3];
            const float ew[8] = {v0.x, v0.z, v1.x, v1.z, v2.x, v2.z, v3.x, v3.z};
            const float ow[8] = {v0.y, v0.w, v1.y, v1.w, v2.y, v2.w, v3.y, v3.w};
            float a[4];
#pragma unroll
            for (int k = 0; k < 4; ++k) {
                float aa = 0.f;
#pragma unroll
                for (int s = 0; s < 4; ++s) {
                    aa = fmaf(ew[k + 1 + s], LO[2 * s], aa);
                    aa = fmaf(ow[k + 1 + s], LO[2 * s + 1], aa);
                }
                a[k] = aa;
            }
            const int m0 = (j0 >> 1) - BPD;
            *reinterpret_cast<float2*>(dstAE + m0) = make_float2(a[0], a[2]);
            *reinterpret_cast<float2*>(dstAO + m0) = make_float2(a[1], a[3]);
        } else {
            for (int k = 0; k < 4; ++k) {
                const int j = j0 + k;
                if (j < S || j >= E) continue;
                float aa = 0.f;
#pragma unroll
                for (int t = 0; t < 8; ++t) {
                    const int idx = symfold(2 * j - 6 + t, SIGLEN);
                    aa = fmaf(xr[idx], LO[t], aa);
                }
                if (j & 1) dstAO[(j >> 1) - BPD] = aa;
                else       dstAE[(j >> 1) - BPD] = aa;
            }
        }
    }
}

// Pool the block's 64 owned buckets of one linear band; 8 threads/bucket.
template<int N, int BASE, int P0>
__device__ __forceinline__ void pool64(const float* __restrict__ buf,
                                       float* __restrict__ dst, int tid) {
    const int p = P0 + (tid >> 3), sub = tid & 7;
    const int s = (p * N) >> 7;
    const int e = ((p + 1) * N + 127) >> 7;
    float acc = 0.f;
    for (int t = s + sub; t < e; t += 8) acc += buf[t - BASE];
    acc += __shfl_xor(acc, 1);
    acc += __shfl_xor(acc, 2);
    acc += __shfl_xor(acc, 4);
    if (sub == 0) dst[p] = acc / (float)(e - s);
}

template<int B>
__device__ __forceinline__ void dwt_body(const float* __restrict__ xr,
                                         float* __restrict__ pr,
                                         float* __restrict__ AE, float* __restrict__ AO,
                                         float* __restrict__ BE, float* __restrict__ BO,
                                         float* __restrict__ D1, float* __restrict__ D2,
                                         int tid) {
    constexpr int p0 = B * 64;
    constexpr int sP5 = (p0 * N5) >> 7, eP5 = ((p0 + 64) * N5 + 127) >> 7;
    constexpr int sP4 = (p0 * N4) >> 7, eP4 = ((p0 + 64) * N4 + 127) >> 7;
    constexpr int sP3 = (p0 * N3) >> 7, eP3 = ((p0 + 64) * N3 + 127) >> 7;
    constexpr int sP2 = (p0 * N2) >> 7, eP2 = ((p0 + 64) * N2 + 127) >> 7;
    constexpr int s5 = sP5, e5 = cmin(eP5, N5);
    constexpr int s4 = cmax(cmin(sP4, 2 * s5 - 6), 0);
    constexpr int e4 = cmin(cmax(eP4, 2 * e5), N4);
    constexpr int s3 = cmax(cmin(sP3, 2 * s4 - 6), 0);
    constexpr int e3 = cmin(cmax(eP3, 2 * e4), N3);
    constexpr int s2 = cmax(cmin(sP2, 2 * s3 - 6), 0);
    constexpr int e2 = cmin(cmax(eP2, 2 * e3), N2);
    constexpr int s1 = cmax(2 * s2 - 6, 0);
    constexpr int e1 = cmin(2 * e2, N1);
    // phase bases (E/O arrays), linear bases (D / cA5)
    constexpr int bp1 = (((s1 >> 1) & ~3) - 4);
    constexpr int bp2 = (((s2 >> 1) & ~3) - 4);
    constexpr int bp3 = (((s3 >> 1) & ~3) - 4);
    constexpr int bp4 = (((s4 >> 1) & ~3) - 4);
    constexpr int bd2 = (s2 & ~3) - 8, bd3 = (s3 & ~3) - 8;
    constexpr int bd4 = (s4 & ~3) - 8, bd5 = (s5 & ~3) - 8;
    constexpr int ba5 = bd5;

    // P0: L1 global -> A phases
    dwt_l1<s1, e1, bp1>(xr, AE, AO, tid);
    __syncthreads();
    // P1: L2: A -> B phases (cA2), D1 linear (cD2)
    dwt_lvl<s1, e1, bp1, N1, s2, e2, bp2, bd2, false>(AE, AO, BE, BO, D1, tid);
    __syncthreads();
    // P2: L3: B -> A phases (cA3), D2 (cD3)   || pool cD2 -> slot 4
    dwt_lvl<s2, e2, bp2, N2, s3, e3, bp3, bd3, false>(BE, BO, AE, AO, D2, tid);
    pool64<N2, bd2, p0>(D1, pr + 4 * POOLP, tid);
    __syncthreads();
    // P3: L4: A -> B phases (cA4), D1 (cD4)   || pool cD3 -> slot 3
    dwt_lvl<s3, e3, bp3, N3, s4, e4, bp4, bd4, false>(AE, AO, BE, BO, D1, tid);
    pool64<N3, bd3, p0>(D2, pr + 3 * POOLP, tid);
    __syncthreads();
    // P4: L5: B -> AE linear (cA5), D2 (cD5)  || pool cD4 -> slot 2
    dwt_lvl<s4, e4, bp4, N4, s5, e5, ba5, bd5, true>(BE, BO, AE, AO, D2, tid);
    pool64<N4, bd4, p0>(D1, pr + 2 * POOLP, tid);
    __syncthreads();
    // P5: pool cA5 -> slot 0, cD5 -> slot 1
    pool64<N5, ba5, p0>(AE, pr + 0 * POOLP, tid);
    pool64<N5, bd5, p0>(D2, pr + 1 * POOLP, tid);
}

__global__ __launch_bounds__(NTHR, 4) void dwt_pool_kernel(const float* __restrict__ x,
                                                           float* __restrict__ pooled) {
    __shared__ __align__(16) float AE[2080], AO[2080];  // cA1/cA3 phases; cA5 linear in AE
    __shared__ __align__(16) float BE[1072], BO[1072];  // cA2/cA4 phases
    __shared__ __align__(16) float D1[2096];            // cD2/cD4 linear
    __shared__ __align__(16) float D2[1072];            // cD3/cD5 linear

    const int tid = threadIdx.x;
    const int row = blockIdx.x >> 1;
    const float* __restrict__ xr = x + (size_t)row * SIGLEN;
    float* __restrict__ pr = pooled + (size_t)row * COMB;

    if (blockIdx.x & 1) dwt_body<1>(xr, pr, AE, AO, BE, BO, D1, D2, tid);
    else                dwt_body<0>(xr, pr, AE, AO, BE, BO, D1, D2, tid);
}

// ---------------- MLP (unchanged from round 8/9/10) ----------------

typedef __fp16 h2 __attribute__((ext_vector_type(2)));

#define LW_PAIRS (5 * 128 * 128 / 2)
#define FW_PAIRS (512 * 640 / 2)

__global__ __launch_bounds__(256) void pack_w(const float* __restrict__ lw,
                                              const float* __restrict__ fw,
                                              h2* __restrict__ lwh,
                                              h2* __restrict__ fwh) {
    const int i = blockIdx.x * 256 + threadIdx.x;
    if (i < LW_PAIRS) {
        const float2 v = reinterpret_cast<const float2*>(lw)[i];
        lwh[i] = __builtin_amdgcn_cvt_pkrtz(v.x, v.y);
    } else if (i < LW_PAIRS + FW_PAIRS) {
        const float2 v = reinterpret_cast<const float2*>(fw)[i - LW_PAIRS];
        fwh[i - LW_PAIRS] = __builtin_amdgcn_cvt_pkrtz(v.x, v.y);
    }
}

__global__ __launch_bounds__(1024, 4) void mlp_kernel(const float* __restrict__ pooled,
                                                      const h2* __restrict__ lwh,
                                                      const float* __restrict__ lb,
                                                      const h2* __restrict__ fwh,
                                                      const float* __restrict__ fb,
                                                      float* __restrict__ out) {
    __shared__ h2 sph[8][COMB / 2];
    __shared__ h2 sch[8][COMB / 2];

    const int tid = threadIdx.x;
    const int r0 = blockIdx.x * 8;

    const float2* __restrict__ srcp = reinterpret_cast<const float2*>(pooled + (size_t)r0 * COMB);
    for (int i = tid; i < 8 * (COMB / 2); i += 1024) {
        const float2 v = srcp[i];
        (&sph[0][0])[i] = __builtin_amdgcn_cvt_pkrtz(v.x, v.y);
    }
    __syncthreads();

    for (int idx = tid; idx < COMB * 2; idx += 1024) {
        const int c = idx >> 1, rh = (idx & 1) * 4;
        const h2* __restrict__ w = lwh + (size_t)c * 64;
        const int lb2 = (c >> 7) * 64;
        const float bias = lb[c];
        float acc[4] = {bias, bias, bias, bias};
        for (int t2 = 0; t2 < 64; t2 += 4) {
            const float4 wraw = *reinterpret_cast<const float4*>(w + t2);
            const h2 w0 = __builtin_bit_cast(h2, wraw.x);
            const h2 w1 = __builtin_bit_cast(h2, wraw.y);
            const h2 w2 = __builtin_bit_cast(h2, wraw.z);
            const h2 w3 = __builtin_bit_cast(h2, wraw.w);
#pragma unroll
            for (int r = 0; r < 4; ++r) {
                const float4 praw = *reinterpret_cast<const float4*>(&sph[rh + r][lb2 + t2]);
                acc[r] = __builtin_amdgcn_fdot2(__builtin_bit_cast(h2, praw.x), w0, acc[r], false);
                acc[r] = __builtin_amdgcn_fdot2(__builtin_bit_cast(h2, praw.y), w1, acc[r], false);
                acc[r] = __builtin_amdgcn_fdot2(__builtin_bit_cast(h2, praw.z), w2, acc[r], false);
                acc[r] = __builtin_amdgcn_fdot2(__builtin_bit_cast(h2, praw.w), w3, acc[r], false);
            }
        }
        __fp16* __restrict__ schf = reinterpret_cast<__fp16*>(&sch[0][0]);
#pragma unroll
        for (int r = 0; r < 4; ++r) schf[(rh + r) * COMB + c] = (__fp16)fmaxf(acc[r], 0.f);
    }
    __syncthreads();

    {
        const int c = tid >> 1, rh = (tid & 1) * 4;
        const h2* __restrict__ w = fwh + (size_t)c * (COMB / 2);
        const float bias = fb[c];
        float acc[4] = {bias, bias, bias, bias};
        for (int t2 = 0; t2 < COMB / 2; t2 += 4) {
            const float4 wraw = *reinterpret_cast<const float4*>(w + t2);
            const h2 w0 = __builtin_bit_cast(h2, wraw.x);
            const h2 w1 = __builtin_bit_cast(h2, wraw.y);
            const h2 w2 = __builtin_bit_cast(h2, wraw.z);
            const h2 w3 = __builtin_bit_cast(h2, wraw.w);
#pragma unroll
            for (int r = 0; r < 4; ++r) {
                const float4 craw = *reinterpret_cast<const float4*>(&sch[rh + r][t2]);
                acc[r] = __builtin_amdgcn_fdot2(__builtin_bit_cast(h2, craw.x), w0, acc[r], false);
                acc[r] = __builtin_amdgcn_fdot2(__builtin_bit_cast(h2, craw.y), w1, acc[r], false);
                acc[r] = __builtin_amdgcn_fdot2(__builtin_bit_cast(h2, craw.z), w2, acc[r], false);
                acc[r] = __builtin_amdgcn_fdot2(__builtin_bit_cast(h2, craw.w), w3, acc[r], false);
            }
        }
#pragma unroll
        for (int r = 0; r < 4; ++r) {
            out[(size_t)(r0 + rh + r) * OUTD + c] = fmaxf(acc[r], 0.f);
        }
    }
}

// Fallback mlp: in-kernel weight cvt — used if d_ws too small for packed weights
__global__ __launch_bounds__(512) void mlp_kernel_fb(const float* __restrict__ pooled,
                                                     const float* __restrict__ lw,
                                                     const float* __restrict__ lb,
                                                     const float* __restrict__ fw,
                                                     const float* __restrict__ fb,
                                                     float* __restrict__ out) {
    __shared__ h2 sph[8][COMB / 2];
    __shared__ h2 sch[8][COMB / 2];
    const int tid = threadIdx.x;
    const int r0 = blockIdx.x * 8;
    const float2* __restrict__ srcp = reinterpret_cast<const float2*>(pooled + (size_t)r0 * COMB);
    for (int i = tid; i < 8 * (COMB / 2); i += 512) {
        const float2 v = srcp[i];
        (&sph[0][0])[i] = __builtin_amdgcn_cvt_pkrtz(v.x, v.y);
    }
    __syncthreads();
    for (int c = tid; c < COMB; c += 512) {
        const float* __restrict__ w = lw + (size_t)c * POOLP;
        const int lb2 = (c >> 7) * (POOLP / 2);
        const float bias = lb[c];
        float acc[8];
#pragma unroll
        for (int r = 0; r < 8; ++r) acc[r] = bias;
        for (int t2 = 0; t2 < POOLP / 2; t2 += 4) {
            const float4 wa = *reinterpret_cast<const float4*>(w + t2 * 2);
            const float4 wb = *reinterpret_cast<const float4*>(w + t2 * 2 + 4);
            const h2 w0 = __builtin_amdgcn_cvt_pkrtz(wa.x, wa.y);
            const h2 w1 = __builtin_amdgcn_cvt_pkrtz(wa.z, wa.w);
            const h2 w2 = __builtin_amdgcn_cvt_pkrtz(wb.x, wb.y);
            const h2 w3 = __builtin_amdgcn_cvt_pkrtz(wb.z, wb.w);
#pragma unroll
            for (int r = 0; r < 8; ++r) {
                const float4 raw = *reinterpret_cast<const float4*>(&sph[r][lb2 + t2]);
                acc[r] = __builtin_amdgcn_fdot2(__builtin_bit_cast(h2, raw.x), w0, acc[r], false);
                acc[r] = __builtin_amdgcn_fdot2(__builtin_bit_cast(h2, raw.y), w1, acc[r], false);
                acc[r] = __builtin_amdgcn_fdot2(__builtin_bit_cast(h2, raw.z), w2, acc[r], false);
                acc[r] = __builtin_amdgcn_fdot2(__builtin_bit_cast(h2, raw.w), w3, acc[r], false);
            }
        }
        __fp16* __restrict__ schf = reinterpret_cast<__fp16*>(&sch[0][0]);
#pragma unroll
        for (int r = 0; r < 8; ++r) schf[r * COMB + c] = (__fp16)fmaxf(acc[r], 0.f);
    }
    __syncthreads();
    {
        const int j = tid;
        const float* __restrict__ w = fw + (size_t)j * COMB;
        const float bias = fb[j];
        float acc[8];
#pragma unroll
        for (int r = 0; r < 8; ++r) acc[r] = bias;
        for (int t2 = 0; t2 < COMB / 2; t2 += 4) {
            const float4 wa = *reinterpret_cast<const float4*>(w + t2 * 2);
            const float4 wb = *reinterpret_cast<const float4*>(w + t2 * 2 + 4);
            const h2 w0 = __builtin_amdgcn_cvt_pkrtz(wa.x, wa.y);
            const h2 w1 = __builtin_amdgcn_cvt_pkrtz(wa.z, wa.w);
            const h2 w2 = __builtin_amdgcn_cvt_pkrtz(wb.x, wb.y);
            const h2 w3 = __builtin_amdgcn_cvt_pkrtz(wb.z, wb.w);
#pragma unroll
            for (int r = 0; r < 8; ++r) {
                const float4 raw = *reinterpret_cast<const float4*>(&sch[r][t2]);
                acc[r] = __builtin_amdgcn_fdot2(__builtin_bit_cast(h2, raw.x), w0, acc[r], false);
                acc[r] = __builtin_amdgcn_fdot2(__builtin_bit_cast(h2, raw.y), w1, acc[r], false);
                acc[r] = __builtin_amdgcn_fdot2(__builtin_bit_cast(h2, raw.z), w2, acc[r], false);
                acc[r] = __builtin_amdgcn_fdot2(__builtin_bit_cast(h2, raw.w), w3, acc[r], false);
            }
        }
#pragma unroll
        for (int r = 0; r < 8; ++r) {
            out[(size_t)(r0 + r) * OUTD + j] = fmaxf(acc[r], 0.f);
        }
    }
}

extern "C" void kernel_launch(void* const* d_in, const int* in_sizes, int n_in,
                              void* d_out, int out_size, void* d_ws, size_t ws_size,
                              hipStream_t stream) {
    const float* x  = (const float*)d_in[0];
    const float* lw = (const float*)d_in[1];
    const float* lb = (const float*)d_in[2];
    const float* fw = (const float*)d_in[3];
    const float* fb = (const float*)d_in[4];
    float* out = (float*)d_out;

    float* pooled = (float*)d_ws;
    const size_t POOLED_B = (size_t)BATCH * COMB * 4;
    const size_t NEEDED   = POOLED_B + (size_t)(LW_PAIRS + FW_PAIRS) * 4;

    dwt_pool_kernel<<<BATCH * 2, NTHR, 0, stream>>>(x, pooled);

    if (ws_size >= NEEDED) {
        h2* lwh = (h2*)((char*)d_ws + POOLED_B);
        h2* fwh = (h2*)((char*)d_ws + POOLED_B + (size_t)LW_PAIRS * 4);
        pack_w<<<(LW_PAIRS + FW_PAIRS + 255) / 256, 256, 0, stream>>>(lw, fw, lwh, fwh);
        mlp_kernel<<<BATCH / 8, 1024, 0, stream>>>(pooled, lwh, lb, fwh, fb, out);
    } else {
        mlp_kernel_fb<<<BATCH / 8, 512, 0, stream>>>(pooled, lw, lb, fw, fb, out);
    }
}